// Round 3
// baseline (480.547 us; speedup 1.0000x reference)
//
#include <hip/hip_runtime.h>
#include <math.h>

#define TRAJ_NUM 25
#define G 200
#define VFOV_RAD 0.3490658503988659f   // deg2rad(20)

#define NPTS 640000          // 6400 traj * 10 t * 10 s
#define WBLKS 2500           // work blocks of 256
#define XCHUNK 313           // ceil(2500/8)

// one thread per LOS point; lane order t-innermost for wave-level request merging
__global__ __launch_bounds__(256) void trackloss_kernel(
    const float* __restrict__ Df,      // [B,3,3]
    const float* __restrict__ Dp,      // [B,3,3]
    const float* __restrict__ goal,    // [B,3]
    const float* __restrict__ L,       // [6,6]
    const float* __restrict__ sdf,     // [M,200,200,200] (z,y,x)
    const float* __restrict__ minb,    // [M,3]
    const int*   __restrict__ map_id,  // [outer]
    float* __restrict__ out)           // [B]
{
    // XCD swizzle: round-robin dispatch (blk % 8 -> XCD) becomes contiguous
    // work ranges per XCD -> same-map outers share an XCD L2
    const int lb   = blockIdx.x;
    const int wblk = (lb & 7) * XCHUNK + (lb >> 3);
    if (wblk >= WBLKS) return;
    const int gid = wblk * 256 + threadIdx.x;   // 0..639999

    const int b   = gid / 100;
    const int r   = gid % 100;
    const int s_i = r / 10;          // LOS sample, 0..9
    const int t_i = r % 10;          // time sample, 0..9 (innermost -> lane-adjacent)
    const int outer = b / TRAJ_NUM;

    const int m = map_id[outer];
    const float gwx = goal[(outer * TRAJ_NUM) * 3 + 0];
    const float gwy = goal[(outer * TRAJ_NUM) * 3 + 1];
    const float gwz = goal[(outer * TRAJ_NUM) * 3 + 2];
    const float mbx = minb[m * 3 + 0];
    const float mby = minb[m * 3 + 1];
    const float mbz = minb[m * 3 + 2];

    // quintic coefficients: coe[c][i] = sum_j L[i][j]*d[c][j]
    float coe[3][6];
    #pragma unroll
    for (int c = 0; c < 3; ++c) {
        float d[6];
        #pragma unroll
        for (int j = 0; j < 3; ++j) {
            d[j]     = Df[b * 9 + c * 3 + j];
            d[j + 3] = Dp[b * 9 + c * 3 + j];
        }
        #pragma unroll
        for (int i = 0; i < 6; ++i) {
            float acc = 0.f;
            #pragma unroll
            for (int j = 0; j < 6; ++j)
                acc += L[i * 6 + j] * d[j];
            coe[c][i] = acc;
        }
    }

    // t = linspace(0.66, 1.32, 10)
    const float t = 0.66f + (float)t_i * (0.66f / 9.0f);

    float p[3];
    #pragma unroll
    for (int c = 0; c < 3; ++c) {
        float pc = coe[c][5];
        pc = pc * t + coe[c][4];
        pc = pc * t + coe[c][3];
        pc = pc * t + coe[c][2];
        pc = pc * t + coe[c][1];
        pc = pc * t + coe[c][0];
        p[c] = pc;
    }

    float val = 0.f;
    if (s_i == 0) {   // pitch penalty once per (b,t)
        float v[3];
        #pragma unroll
        for (int c = 0; c < 3; ++c) {
            float vc = 5.f * coe[c][5];
            vc = vc * t + 4.f * coe[c][4];
            vc = vc * t + 3.f * coe[c][3];
            vc = vc * t + 2.f * coe[c][2];
            vc = vc * t + 1.f * coe[c][1];
            v[c] = vc;
        }
        const float gdx = gwx - p[0], gdy = gwy - p[1], gdz = gwz - p[2];
        const float pitch_g = atan2f(gdz, sqrtf(gdx * gdx + gdy * gdy + 1e-6f));
        const float pitch_v = atan2f(v[2], sqrtf(v[0] * v[0] + v[1] * v[1] + 1e-6f));
        val = fmaxf(fabsf(pitch_g - pitch_v) - VFOV_RAD, 0.f) * 0.5f;
    }

    // LOS point s_i: vox = (p - mb)/0.2 + s_i * (g - p)/(0.2*9)
    const float tt = (float)s_i;
    const float gx = (p[0] - mbx) * 5.0f + tt * ((gwx - p[0]) * (5.0f / 9.0f));
    const float gy = (p[1] - mby) * 5.0f + tt * ((gwy - p[1]) * (5.0f / 9.0f));
    const float gz = (p[2] - mbz) * 5.0f + tt * ((gwz - p[2]) * (5.0f / 9.0f));

    const bool valid = (gx > 0.5f) & (gx < (float)G - 1.5f) &
                       (gy > 0.5f) & (gy < (float)G - 1.5f) &
                       (gz > 0.5f) & (gz < (float)G - 1.5f);

    const int x0 = (int)fminf(fmaxf(floorf(gx), 0.f), (float)(G - 2));
    const int y0 = (int)fminf(fmaxf(floorf(gy), 0.f), (float)(G - 2));
    const int z0 = (int)fminf(fmaxf(floorf(gz), 0.f), (float)(G - 2));
    const float fx = gx - (float)x0;
    const float fy = gy - (float)y0;
    const float fz = gz - (float)z0;

    const int base = ((m * G + z0) * G + y0) * G + x0;
    const float* pB = sdf + base;
    const float c000 = pB[0];
    const float c001 = pB[1];
    const float c010 = pB[G];
    const float c011 = pB[G + 1];
    const float c100 = pB[G * G];
    const float c101 = pB[G * G + 1];
    const float c110 = pB[G * G + G];
    const float c111 = pB[G * G + G + 1];

    const float c0 = (c000 * (1.f - fx) + c001 * fx) * (1.f - fy)
                   + (c010 * (1.f - fx) + c011 * fx) * fy;
    const float c1 = (c100 * (1.f - fx) + c101 * fx) * (1.f - fy)
                   + (c110 * (1.f - fx) + c111 * fx) * fy;
    const float dist = c0 * (1.f - fz) + c1 * fz;

    const float cost = valid ? expf((0.6f - dist) * (1.f / 0.3f)) : 0.f;
    val += fmaxf(0.2f - cost, 0.f) * 0.2f;   // occ contribution, scale 4*5/100

    atomicAdd(&out[b], val);
}

extern "C" void kernel_launch(void* const* d_in, const int* in_sizes, int n_in,
                              void* d_out, int out_size, void* d_ws, size_t ws_size,
                              hipStream_t stream) {
    const float* Df     = (const float*)d_in[0];
    const float* Dp     = (const float*)d_in[1];
    const float* goal   = (const float*)d_in[2];
    const float* L      = (const float*)d_in[3];
    const float* sdf    = (const float*)d_in[4];
    const float* minb   = (const float*)d_in[5];
    const int*   map_id = (const int*)d_in[6];
    float* out = (float*)d_out;

    hipMemsetAsync(out, 0, out_size * sizeof(float), stream);
    trackloss_kernel<<<XCHUNK * 8, 256, 0, stream>>>(Df, Dp, goal, L, sdf, minb, map_id, out);
}

// Round 4
// 318.432 us; speedup vs baseline: 1.5091x; 1.5091x over previous
//
#include <hip/hip_runtime.h>
#include <math.h>

#define TRAJ_NUM 25
#define G 200
#define VFOV_RAD 0.3490658503988659f   // deg2rad(20)

#define NPTS 640000          // 6400 traj * 10 t * 10 s
#define WBLKS 2500           // blocks of 256, one thread per point

// one thread per LOS point; lane order t-innermost so t-adjacent points share
// cachelines within a wave (merged L2 requests -> FETCH_SIZE ~= unique lines)
__global__ __launch_bounds__(256) void trackloss_kernel(
    const float* __restrict__ Df,      // [B,3,3]
    const float* __restrict__ Dp,      // [B,3,3]
    const float* __restrict__ goal,    // [B,3]
    const float* __restrict__ L,       // [6,6]
    const float* __restrict__ sdf,     // [M,200,200,200] (z,y,x)
    const float* __restrict__ minb,    // [M,3]
    const int*   __restrict__ map_id,  // [outer]
    float* __restrict__ out)           // [B]
{
    const int gid = blockIdx.x * 256 + threadIdx.x;   // 0..639999

    const int b   = gid / 100;
    const int r   = gid % 100;
    const int s_i = r / 10;          // LOS sample, 0..9
    const int t_i = r % 10;          // time sample, 0..9 (innermost -> lane-adjacent)
    const int outer = b / TRAJ_NUM;

    const int m = map_id[outer];
    const float gwx = goal[(outer * TRAJ_NUM) * 3 + 0];
    const float gwy = goal[(outer * TRAJ_NUM) * 3 + 1];
    const float gwz = goal[(outer * TRAJ_NUM) * 3 + 2];
    const float mbx = minb[m * 3 + 0];
    const float mby = minb[m * 3 + 1];
    const float mbz = minb[m * 3 + 2];

    // quintic coefficients: coe[c][i] = sum_j L[i][j]*d[c][j]
    float coe[3][6];
    #pragma unroll
    for (int c = 0; c < 3; ++c) {
        float d[6];
        #pragma unroll
        for (int j = 0; j < 3; ++j) {
            d[j]     = Df[b * 9 + c * 3 + j];
            d[j + 3] = Dp[b * 9 + c * 3 + j];
        }
        #pragma unroll
        for (int i = 0; i < 6; ++i) {
            float acc = 0.f;
            #pragma unroll
            for (int j = 0; j < 6; ++j)
                acc += L[i * 6 + j] * d[j];
            coe[c][i] = acc;
        }
    }

    // t = linspace(0.66, 1.32, 10)
    const float t = 0.66f + (float)t_i * (0.66f / 9.0f);

    float p[3];
    #pragma unroll
    for (int c = 0; c < 3; ++c) {
        float pc = coe[c][5];
        pc = pc * t + coe[c][4];
        pc = pc * t + coe[c][3];
        pc = pc * t + coe[c][2];
        pc = pc * t + coe[c][1];
        pc = pc * t + coe[c][0];
        p[c] = pc;
    }

    float val = 0.f;
    if (s_i == 0) {   // pitch penalty once per (b,t)
        float v[3];
        #pragma unroll
        for (int c = 0; c < 3; ++c) {
            float vc = 5.f * coe[c][5];
            vc = vc * t + 4.f * coe[c][4];
            vc = vc * t + 3.f * coe[c][3];
            vc = vc * t + 2.f * coe[c][2];
            vc = vc * t + 1.f * coe[c][1];
            v[c] = vc;
        }
        const float gdx = gwx - p[0], gdy = gwy - p[1], gdz = gwz - p[2];
        const float pitch_g = atan2f(gdz, sqrtf(gdx * gdx + gdy * gdy + 1e-6f));
        const float pitch_v = atan2f(v[2], sqrtf(v[0] * v[0] + v[1] * v[1] + 1e-6f));
        val = fmaxf(fabsf(pitch_g - pitch_v) - VFOV_RAD, 0.f) * 0.5f;
    }

    // LOS point s_i: vox = (p - mb)/0.2 + s_i * (g - p)/(0.2*9)
    const float tt = (float)s_i;
    const float gx = (p[0] - mbx) * 5.0f + tt * ((gwx - p[0]) * (5.0f / 9.0f));
    const float gy = (p[1] - mby) * 5.0f + tt * ((gwy - p[1]) * (5.0f / 9.0f));
    const float gz = (p[2] - mbz) * 5.0f + tt * ((gwz - p[2]) * (5.0f / 9.0f));

    const bool valid = (gx > 0.5f) & (gx < (float)G - 1.5f) &
                       (gy > 0.5f) & (gy < (float)G - 1.5f) &
                       (gz > 0.5f) & (gz < (float)G - 1.5f);

    if (valid) {
        const int x0 = (int)gx;          // in (0.5, 198.5) -> floor == trunc, in-range
        const int y0 = (int)gy;
        const int z0 = (int)gz;
        const float fx = gx - (float)x0;
        const float fy = gy - (float)y0;
        const float fz = gz - (float)z0;

        const int base = ((m * G + z0) * G + y0) * G + x0;
        const float* pB = sdf + base;
        const float c000 = pB[0];
        const float c001 = pB[1];
        const float c010 = pB[G];
        const float c011 = pB[G + 1];
        const float c100 = pB[G * G];
        const float c101 = pB[G * G + 1];
        const float c110 = pB[G * G + G];
        const float c111 = pB[G * G + G + 1];

        const float c0 = (c000 * (1.f - fx) + c001 * fx) * (1.f - fy)
                       + (c010 * (1.f - fx) + c011 * fx) * fy;
        const float c1 = (c100 * (1.f - fx) + c101 * fx) * (1.f - fy)
                       + (c110 * (1.f - fx) + c111 * fx) * fy;
        const float dist = c0 * (1.f - fz) + c1 * fz;
        const float cost = expf((0.6f - dist) * (1.f / 0.3f));
        val += fmaxf(0.2f - cost, 0.f) * 0.2f;   // occ contribution, scale 4*5/100
    } else {
        val += 0.2f * 0.2f;                       // cost==0 -> relu(0.2-0) = 0.2
    }

    // segmented wave reduction: 64 consecutive gids span at most 2 trajectories
    // (boundary every 100 gids), so reduce two accumulators per wave.
    const int lane = threadIdx.x & 63;
    const int b_first = __shfl(b, 0, 64);
    const int b_last  = __shfl(b, 63, 64);
    float vA = (b == b_first) ? val : 0.f;
    float vB = (b == b_first) ? 0.f : val;
    #pragma unroll
    for (int off = 1; off < 64; off <<= 1) {
        vA += __shfl_xor(vA, off, 64);
        vB += __shfl_xor(vB, off, 64);
    }
    if (lane == 0) {
        atomicAdd(&out[b_first], vA);                         // <=3 contenders
        if (b_last != b_first) atomicAdd(&out[b_last], vB);
    }
}

extern "C" void kernel_launch(void* const* d_in, const int* in_sizes, int n_in,
                              void* d_out, int out_size, void* d_ws, size_t ws_size,
                              hipStream_t stream) {
    const float* Df     = (const float*)d_in[0];
    const float* Dp     = (const float*)d_in[1];
    const float* goal   = (const float*)d_in[2];
    const float* L      = (const float*)d_in[3];
    const float* sdf    = (const float*)d_in[4];
    const float* minb   = (const float*)d_in[5];
    const int*   map_id = (const int*)d_in[6];
    float* out = (float*)d_out;

    hipMemsetAsync(out, 0, out_size * sizeof(float), stream);
    trackloss_kernel<<<WBLKS, 256, 0, stream>>>(Df, Dp, goal, L, sdf, minb, map_id, out);
}